// Round 3
// baseline (40427.390 us; speedup 1.0000x reference)
//
#include <hip/hip_runtime.h>

// Problem constants
#define T_STEPS 2048
#define BATCH   64
#define ISZ     512
#define HSZ     256
#define G4      1024   // 4*H
#define OSZ     128

typedef __attribute__((ext_vector_type(8))) short short8;
typedef __attribute__((ext_vector_type(4))) float f32x4;

__device__ __forceinline__ unsigned short f32_to_bf16(float x) {
  unsigned int u = __float_as_uint(x);
  unsigned int r = (u + 0x7FFFu + ((u >> 16) & 1u)) >> 16;  // RTNE
  return (unsigned short)r;
}
__device__ __forceinline__ float bf16_to_f32(unsigned short s) {
  return __uint_as_float(((unsigned int)s) << 16);
}
__device__ __forceinline__ float tanh_fast(float x) {
  return 1.f - 2.f / (__expf(2.f * x) + 1.f);
}

// ---------------------------------------------------------------------------
// fp32 -> bf16 hi + bf16 residual lo. n must be %4.
// ---------------------------------------------------------------------------
__global__ void split_bf16_kernel(const float* __restrict__ src,
                                  short* __restrict__ hi, short* __restrict__ lo,
                                  long n) {
  long i = ((long)blockIdx.x * blockDim.x + threadIdx.x) * 4;
  if (i >= n) return;
  float4 v = *(const float4*)(src + i);
  float xs[4] = {v.x, v.y, v.z, v.w};
  short h[4], l[4];
#pragma unroll
  for (int j = 0; j < 4; ++j) {
    unsigned short hb = f32_to_bf16(xs[j]);
    float hf = bf16_to_f32(hb);
    unsigned short lb = f32_to_bf16(xs[j] - hf);
    h[j] = (short)hb; l[j] = (short)lb;
  }
  *(short4*)(hi + i) = make_short4(h[0], h[1], h[2], h[3]);
  *(short4*)(lo + i) = make_short4(l[0], l[1], l[2], l[3]);
}

// ---------------------------------------------------------------------------
// Split-bf16 GEMM: C[M][N] = A[M][K]*B[N][K]^T + bias1 (+bias2), fp32 out.
// hi*hi + lo*hi + hi*lo  ~= fp32 precision. WG=4 waves, tile 64x64.
// MFMA 16x16x32 bf16: A lane: m=lane&15, k=(lane>>4)*8+j (B same with n)
//                     D: row=(lane>>4)*4+r, col=lane&15   [verified m89]
// ---------------------------------------------------------------------------
__global__ __launch_bounds__(256) void gemm_bf16x3(
    const short* __restrict__ Ahi, const short* __restrict__ Alo,
    const short* __restrict__ Bhi, const short* __restrict__ Blo,
    const float* __restrict__ bias1, const float* __restrict__ bias2,
    float* __restrict__ C, int N, int K) {
  const int tid  = threadIdx.x;
  const int lane = tid & 63;
  const int wv   = tid >> 6;
  const int lrow = lane & 15;
  const int kgrp = lane >> 4;
  const int m0 = blockIdx.x * 64 + wv * 16;
  const int n0 = blockIdx.y * 64;

  const short* pah = Ahi + (size_t)(m0 + lrow) * K + kgrp * 8;
  const short* pal = Alo + (size_t)(m0 + lrow) * K + kgrp * 8;
  const short* pbh = Bhi + (size_t)(n0 + lrow) * K + kgrp * 8;
  const short* pbl = Blo + (size_t)(n0 + lrow) * K + kgrp * 8;
  const size_t cs = (size_t)16 * K;

  f32x4 acc0 = {0.f, 0.f, 0.f, 0.f};
  f32x4 acc1 = acc0, acc2 = acc0, acc3 = acc0;

  for (int kb = 0; kb < K; kb += 32) {
    short8 ah  = *(const short8*)(pah + kb);
    short8 al  = *(const short8*)(pal + kb);
    short8 b0h = *(const short8*)(pbh + kb);
    short8 b0l = *(const short8*)(pbl + kb);
    short8 b1h = *(const short8*)(pbh + cs + kb);
    short8 b1l = *(const short8*)(pbl + cs + kb);
    short8 b2h = *(const short8*)(pbh + 2 * cs + kb);
    short8 b2l = *(const short8*)(pbl + 2 * cs + kb);
    short8 b3h = *(const short8*)(pbh + 3 * cs + kb);
    short8 b3l = *(const short8*)(pbl + 3 * cs + kb);

    acc0 = __builtin_amdgcn_mfma_f32_16x16x32_bf16(ah, b0h, acc0, 0, 0, 0);
    acc1 = __builtin_amdgcn_mfma_f32_16x16x32_bf16(ah, b1h, acc1, 0, 0, 0);
    acc2 = __builtin_amdgcn_mfma_f32_16x16x32_bf16(ah, b2h, acc2, 0, 0, 0);
    acc3 = __builtin_amdgcn_mfma_f32_16x16x32_bf16(ah, b3h, acc3, 0, 0, 0);
    acc0 = __builtin_amdgcn_mfma_f32_16x16x32_bf16(al, b0h, acc0, 0, 0, 0);
    acc1 = __builtin_amdgcn_mfma_f32_16x16x32_bf16(al, b1h, acc1, 0, 0, 0);
    acc2 = __builtin_amdgcn_mfma_f32_16x16x32_bf16(al, b2h, acc2, 0, 0, 0);
    acc3 = __builtin_amdgcn_mfma_f32_16x16x32_bf16(al, b3h, acc3, 0, 0, 0);
    acc0 = __builtin_amdgcn_mfma_f32_16x16x32_bf16(ah, b0l, acc0, 0, 0, 0);
    acc1 = __builtin_amdgcn_mfma_f32_16x16x32_bf16(ah, b1l, acc1, 0, 0, 0);
    acc2 = __builtin_amdgcn_mfma_f32_16x16x32_bf16(ah, b2l, acc2, 0, 0, 0);
    acc3 = __builtin_amdgcn_mfma_f32_16x16x32_bf16(ah, b3l, acc3, 0, 0, 0);
  }

  f32x4 accs[4] = {acc0, acc1, acc2, acc3};
#pragma unroll
  for (int c = 0; c < 4; ++c) {
    const int col = n0 + c * 16 + lrow;
    float bs = bias1[col];
    if (bias2) bs += bias2[col];
#pragma unroll
    for (int r = 0; r < 4; ++r) {
      const int row = m0 + kgrp * 4 + r;
      C[(size_t)row * N + col] = accs[c][r] + bs;
    }
  }
}

// ---------------------------------------------------------------------------
// LSTM recurrence: ONE 1024-thread WG per batch element (64 WGs total).
// Thread tid == W_hh row j (gate q = tid>>8, hidx = tid&255); each thread
// holds its full 256-wide weight row in regs (compiler: ~144 VGPR + 256
// AGPR, as measured in the 256-thread variant). 16 waves x ~400 regs fits
// the 2048-reg/SIMD pool at 4 waves/SIMD -> whole block resident on 1 CU.
// h exchange is now PURE LDS + __syncthreads: no cross-WG traffic, no
// atomics, no polling. 2 barriers per step.
// ---------------------------------------------------------------------------
__global__ __launch_bounds__(1024) void lstm_rec(
    const float* __restrict__ G,        // [nsteps][B][1024] (chunk)
    const float* __restrict__ Whh,      // [1024][256]
    short* __restrict__ HShi, short* __restrict__ HSlo,  // [nsteps][B][256]
    float* __restrict__ h_buf,          // [B][256] chunk-boundary h
    float* __restrict__ c_buf,          // [B][256] chunk-boundary c
    int t0, int nsteps) {
  const int tid  = threadIdx.x;   // 0..1023 == W_hh row index j
  const int b    = blockIdx.x;    // batch element
  const int q    = tid >> 8;      // gate: 0=i 1=f 2=g 3=o (wave-uniform)
  const int hidx = tid & 255;

  float w[256];
  {
    const float* wr = Whh + (size_t)tid * 256;
#pragma unroll
    for (int k = 0; k < 256; k += 4) {
      float4 v = *(const float4*)(wr + k);
      w[k] = v.x; w[k + 1] = v.y; w[k + 2] = v.z; w[k + 3] = v.w;
    }
  }

  __shared__ float4 h_s4[64];
  float* h_s = (float*)h_s4;
  __shared__ float gate_s[4][256];

  // ---- initial h/c ----
  if (t0 == 0) {
    if (tid < 64) h_s4[tid] = make_float4(0.f, 0.f, 0.f, 0.f);
  } else {
    if (tid < 64) h_s4[tid] = *(const float4*)(h_buf + (size_t)b * HSZ + tid * 4);
  }
  float c = 0.f;
  if (q == 0 && t0 > 0) c = c_buf[(size_t)b * HSZ + hidx];

  const float* gbase = G + (size_t)b * G4 + tid;
  float gcur = gbase[0];
  __syncthreads();

  for (int t = 0; t < nsteps; ++t) {
    const size_t tn = (t + 1 < nsteps) ? (size_t)(t + 1) : (size_t)(nsteps - 1);
    const float gnx = gbase[tn * (size_t)(BATCH * G4)];  // prefetch next step

    float a0 = 0.f, a1 = 0.f, a2 = 0.f, a3 = 0.f;
#pragma unroll
    for (int k = 0; k < 256; k += 4) {
      const float4 hv = h_s4[k >> 2];   // wave-uniform LDS broadcast
      a0 = __builtin_fmaf(hv.x, w[k],     a0);
      a1 = __builtin_fmaf(hv.y, w[k + 1], a1);
      a2 = __builtin_fmaf(hv.z, w[k + 2], a2);
      a3 = __builtin_fmaf(hv.w, w[k + 3], a3);
    }
    const float pre = gcur + ((a0 + a1) + (a2 + a3));
    // per-wave activation: waves with q==2 tanh, others sigmoid (uniform)
    gate_s[q][hidx] = (q == 2) ? tanh_fast(pre) : 1.f / (1.f + __expf(-pre));
    gcur = gnx;
    __syncthreads();  // (1) activated gates ready; h_s reads done

    if (q == 0) {
      const float si = gate_s[0][hidx];
      const float sf = gate_s[1][hidx];
      const float tg = gate_s[2][hidx];
      const float so = gate_s[3][hidx];
      c = sf * c + si * tg;
      const float h = so * tanh_fast(c);
      const size_t oidx = ((size_t)t * BATCH + b) * HSZ + hidx;
      const unsigned short hb = f32_to_bf16(h);
      const unsigned short lb = f32_to_bf16(h - bf16_to_f32(hb));
      HShi[oidx] = (short)hb;
      HSlo[oidx] = (short)lb;
      h_s[hidx] = h;                    // next step's h, all in-CU
    }
    __syncthreads();  // (2) h_s ready for next step
  }

  if (q == 0) {
    c_buf[(size_t)b * HSZ + hidx] = c;        // persist across chunks
    h_buf[(size_t)b * HSZ + hidx] = h_s[hidx];
  }
}

// ---------------------------------------------------------------------------
// kernel_launch: chunked pipeline sized to ws_size.
// Per chunk (CH steps): split X -> GEMM (G = X@Wih^T + bih + bhh)
//                       -> lstm_rec -> FC (out = HS@Wfc^T + bfc)
// ---------------------------------------------------------------------------
extern "C" void kernel_launch(void* const* d_in, const int* in_sizes, int n_in,
                              void* d_out, int out_size, void* d_ws, size_t ws_size,
                              hipStream_t stream) {
  (void)in_sizes; (void)n_in; (void)out_size;
  const float* X   = (const float*)d_in[0];
  const float* Wih = (const float*)d_in[1];
  const float* Whh = (const float*)d_in[2];
  const float* bih = (const float*)d_in[3];
  const float* bhh = (const float*)d_in[4];
  const float* Wfc = (const float*)d_in[5];
  const float* bfc = (const float*)d_in[6];
  float* out = (float*)d_out;

  // ---- choose chunk size (largest pow2 dividing T that fits ws_size) ----
  const size_t fixed =
      2UL * 1048576UL   /* Wih hi+lo  */ +
      2UL * 65536UL     /* Wfc hi+lo  */ +
      65536UL           /* h_buf      */ +
      65536UL;          /* c_buf      */
  const size_t per_step =
      (size_t)BATCH * G4 * 4   /* Gc   262144 */ +
      2UL * BATCH * ISZ * 2    /* Xhi+Xlo 131072 */ +
      2UL * BATCH * HSZ * 2    /* HShi+HSlo 65536 */;
  int CH = 2048;
  while (CH > 16 && fixed + (size_t)CH * per_step > ws_size) CH >>= 1;

  // ---- workspace layout ----
  char* p = (char*)d_ws;
  float* Gc    = (float*)p;  p += (size_t)CH * BATCH * G4 * 4;
  short* Xhi   = (short*)p;  p += (size_t)CH * BATCH * ISZ * 2;
  short* Xlo   = (short*)p;  p += (size_t)CH * BATCH * ISZ * 2;
  short* HShi  = (short*)p;  p += (size_t)CH * BATCH * HSZ * 2;
  short* HSlo  = (short*)p;  p += (size_t)CH * BATCH * HSZ * 2;
  short* WihHi = (short*)p;  p += 1048576UL;
  short* WihLo = (short*)p;  p += 1048576UL;
  short* WfcHi = (short*)p;  p += 65536UL;
  short* WfcLo = (short*)p;  p += 65536UL;
  float* h_buf = (float*)p;  p += 65536UL;
  float* c_buf = (float*)p;

  // weight splits
  split_bf16_kernel<<<512, 256, 0, stream>>>(Wih, WihHi, WihLo, 524288L);
  split_bf16_kernel<<<32, 256, 0, stream>>>(Wfc, WfcHi, WfcLo, 32768L);

  const long xchunk_elems = (long)CH * BATCH * ISZ;   // CH*32768
  for (int c0 = 0; c0 < T_STEPS; c0 += CH) {
    const float* Xc = X + (size_t)c0 * BATCH * ISZ;
    split_bf16_kernel<<<(int)(xchunk_elems / 1024), 256, 0, stream>>>(
        Xc, Xhi, Xlo, xchunk_elems);
    // G = Xc @ Wih^T + (bih + bhh)  [M=CH*64, N=1024, K=512]
    gemm_bf16x3<<<dim3(CH, 16), 256, 0, stream>>>(Xhi, Xlo, WihHi, WihLo,
                                                  bih, bhh, Gc, 1024, 512);
    lstm_rec<<<BATCH, 1024, 0, stream>>>(Gc, Whh, HShi, HSlo, h_buf, c_buf,
                                         c0, CH);
    // out_chunk = HS @ Wfc^T + bfc  [M=CH*64, N=128, K=256]
    gemm_bf16x3<<<dim3(CH, 2), 256, 0, stream>>>(HShi, HSlo, WfcHi, WfcLo,
                                                 bfc, nullptr,
                                                 out + (size_t)c0 * BATCH * OSZ,
                                                 128, 256);
  }
}

// Round 4
// 9986.716 us; speedup vs baseline: 4.0481x; 4.0481x over previous
//
#include <hip/hip_runtime.h>

// Problem constants
#define T_STEPS 2048
#define BATCH   64
#define ISZ     512
#define HSZ     256
#define G4      1024   // 4*H
#define OSZ     128
#define RING_D  64     // LDS G-ring depth (steps), power of 2, multiple of 16

typedef __attribute__((ext_vector_type(8))) short short8;
typedef __attribute__((ext_vector_type(4))) float f32x4;

__device__ __forceinline__ unsigned short f32_to_bf16(float x) {
  unsigned int u = __float_as_uint(x);
  unsigned int r = (u + 0x7FFFu + ((u >> 16) & 1u)) >> 16;  // RTNE
  return (unsigned short)r;
}
__device__ __forceinline__ float bf16_to_f32(unsigned short s) {
  return __uint_as_float(((unsigned int)s) << 16);
}
__device__ __forceinline__ float tanh_fast(float x) {
  return 1.f - 2.f / (__expf(2.f * x) + 1.f);
}

// ---------------------------------------------------------------------------
// fp32 -> bf16 hi + bf16 residual lo. n must be %4.
// ---------------------------------------------------------------------------
__global__ void split_bf16_kernel(const float* __restrict__ src,
                                  short* __restrict__ hi, short* __restrict__ lo,
                                  long n) {
  long i = ((long)blockIdx.x * blockDim.x + threadIdx.x) * 4;
  if (i >= n) return;
  float4 v = *(const float4*)(src + i);
  float xs[4] = {v.x, v.y, v.z, v.w};
  short h[4], l[4];
#pragma unroll
  for (int j = 0; j < 4; ++j) {
    unsigned short hb = f32_to_bf16(xs[j]);
    float hf = bf16_to_f32(hb);
    unsigned short lb = f32_to_bf16(xs[j] - hf);
    h[j] = (short)hb; l[j] = (short)lb;
  }
  *(short4*)(hi + i) = make_short4(h[0], h[1], h[2], h[3]);
  *(short4*)(lo + i) = make_short4(l[0], l[1], l[2], l[3]);
}

__global__ void zero_u32_kernel(unsigned int* __restrict__ p, int n) {
  int i = blockIdx.x * blockDim.x + threadIdx.x;
  if (i < n) p[i] = 0u;
}

// ---------------------------------------------------------------------------
// Split-bf16 GEMM (kept for the FC epilogue): C = A*B^T + bias, fp32 out.
// ---------------------------------------------------------------------------
__global__ __launch_bounds__(256) void gemm_bf16x3(
    const short* __restrict__ Ahi, const short* __restrict__ Alo,
    const short* __restrict__ Bhi, const short* __restrict__ Blo,
    const float* __restrict__ bias1, const float* __restrict__ bias2,
    float* __restrict__ C, int N, int K) {
  const int tid  = threadIdx.x;
  const int lane = tid & 63;
  const int wv   = tid >> 6;
  const int lrow = lane & 15;
  const int kgrp = lane >> 4;
  const int m0 = blockIdx.x * 64 + wv * 16;
  const int n0 = blockIdx.y * 64;

  const short* pah = Ahi + (size_t)(m0 + lrow) * K + kgrp * 8;
  const short* pal = Alo + (size_t)(m0 + lrow) * K + kgrp * 8;
  const short* pbh = Bhi + (size_t)(n0 + lrow) * K + kgrp * 8;
  const short* pbl = Blo + (size_t)(n0 + lrow) * K + kgrp * 8;
  const size_t cs = (size_t)16 * K;

  f32x4 acc0 = {0.f, 0.f, 0.f, 0.f};
  f32x4 acc1 = acc0, acc2 = acc0, acc3 = acc0;

  for (int kb = 0; kb < K; kb += 32) {
    short8 ah  = *(const short8*)(pah + kb);
    short8 al  = *(const short8*)(pal + kb);
    short8 b0h = *(const short8*)(pbh + kb);
    short8 b0l = *(const short8*)(pbl + kb);
    short8 b1h = *(const short8*)(pbh + cs + kb);
    short8 b1l = *(const short8*)(pbl + cs + kb);
    short8 b2h = *(const short8*)(pbh + 2 * cs + kb);
    short8 b2l = *(const short8*)(pbl + 2 * cs + kb);
    short8 b3h = *(const short8*)(pbh + 3 * cs + kb);
    short8 b3l = *(const short8*)(pbl + 3 * cs + kb);

    acc0 = __builtin_amdgcn_mfma_f32_16x16x32_bf16(ah, b0h, acc0, 0, 0, 0);
    acc1 = __builtin_amdgcn_mfma_f32_16x16x32_bf16(ah, b1h, acc1, 0, 0, 0);
    acc2 = __builtin_amdgcn_mfma_f32_16x16x32_bf16(ah, b2h, acc2, 0, 0, 0);
    acc3 = __builtin_amdgcn_mfma_f32_16x16x32_bf16(ah, b3h, acc3, 0, 0, 0);
    acc0 = __builtin_amdgcn_mfma_f32_16x16x32_bf16(al, b0h, acc0, 0, 0, 0);
    acc1 = __builtin_amdgcn_mfma_f32_16x16x32_bf16(al, b1h, acc1, 0, 0, 0);
    acc2 = __builtin_amdgcn_mfma_f32_16x16x32_bf16(al, b2h, acc2, 0, 0, 0);
    acc3 = __builtin_amdgcn_mfma_f32_16x16x32_bf16(al, b3h, acc3, 0, 0, 0);
    acc0 = __builtin_amdgcn_mfma_f32_16x16x32_bf16(ah, b0l, acc0, 0, 0, 0);
    acc1 = __builtin_amdgcn_mfma_f32_16x16x32_bf16(ah, b1l, acc1, 0, 0, 0);
    acc2 = __builtin_amdgcn_mfma_f32_16x16x32_bf16(ah, b2l, acc2, 0, 0, 0);
    acc3 = __builtin_amdgcn_mfma_f32_16x16x32_bf16(ah, b3l, acc3, 0, 0, 0);
  }

  f32x4 accs[4] = {acc0, acc1, acc2, acc3};
#pragma unroll
  for (int c = 0; c < 4; ++c) {
    const int col = n0 + c * 16 + lrow;
    float bs = bias1[col];
    if (bias2) bs += bias2[col];
#pragma unroll
    for (int r = 0; r < 4; ++r) {
      const int row = m0 + kgrp * 4 + r;
      C[(size_t)row * N + col] = accs[c][r] + bs;
    }
  }
}

// ---------------------------------------------------------------------------
// G-tile production (fused input GEMM): one wave computes its gate q's 64
// G-rows for 16 steps [tstep, tstep+16) via the SAME bf16x3 MFMA chain and
// accumulation order as gemm_bf16x3 (bit-identical values), writing fp32
// results into the wave-private region of the LDS ring.
// A-frag: m = step offset (lane&15); B-frag: n = Wih-row offset (lane&15).
// ---------------------------------------------------------------------------
__device__ __forceinline__ void produce_gtile(
    const short* __restrict__ Xhi, const short* __restrict__ Xlo,
    const short* __restrict__ WihHi, const short* __restrict__ WihLo,
    float* __restrict__ ring, int tstep, int b, int q, int part, int lane) {
  const int m  = lane & 15;
  const int kg = lane >> 4;
  const size_t xoff = ((size_t)(tstep + m) * BATCH + b) * ISZ + kg * 8;
  const short* xh = Xhi + xoff;
  const short* xl = Xlo + xoff;
  const size_t roff = (size_t)(q * 256 + part * 64 + m) * ISZ + kg * 8;
  const short* bh0 = WihHi + roff;
  const short* bl0 = WihLo + roff;
  const size_t nts = (size_t)16 * ISZ;

  f32x4 acc0 = {0.f, 0.f, 0.f, 0.f};
  f32x4 acc1 = acc0, acc2 = acc0, acc3 = acc0;

  for (int kb = 0; kb < ISZ; kb += 32) {
    short8 ah  = *(const short8*)(xh + kb);
    short8 al  = *(const short8*)(xl + kb);
    short8 b0h = *(const short8*)(bh0 + kb);
    short8 b0l = *(const short8*)(bl0 + kb);
    short8 b1h = *(const short8*)(bh0 + nts + kb);
    short8 b1l = *(const short8*)(bl0 + nts + kb);
    short8 b2h = *(const short8*)(bh0 + 2 * nts + kb);
    short8 b2l = *(const short8*)(bl0 + 2 * nts + kb);
    short8 b3h = *(const short8*)(bh0 + 3 * nts + kb);
    short8 b3l = *(const short8*)(bl0 + 3 * nts + kb);

    acc0 = __builtin_amdgcn_mfma_f32_16x16x32_bf16(ah, b0h, acc0, 0, 0, 0);
    acc1 = __builtin_amdgcn_mfma_f32_16x16x32_bf16(ah, b1h, acc1, 0, 0, 0);
    acc2 = __builtin_amdgcn_mfma_f32_16x16x32_bf16(ah, b2h, acc2, 0, 0, 0);
    acc3 = __builtin_amdgcn_mfma_f32_16x16x32_bf16(ah, b3h, acc3, 0, 0, 0);
    acc0 = __builtin_amdgcn_mfma_f32_16x16x32_bf16(al, b0h, acc0, 0, 0, 0);
    acc1 = __builtin_amdgcn_mfma_f32_16x16x32_bf16(al, b1h, acc1, 0, 0, 0);
    acc2 = __builtin_amdgcn_mfma_f32_16x16x32_bf16(al, b2h, acc2, 0, 0, 0);
    acc3 = __builtin_amdgcn_mfma_f32_16x16x32_bf16(al, b3h, acc3, 0, 0, 0);
    acc0 = __builtin_amdgcn_mfma_f32_16x16x32_bf16(ah, b0l, acc0, 0, 0, 0);
    acc1 = __builtin_amdgcn_mfma_f32_16x16x32_bf16(ah, b1l, acc1, 0, 0, 0);
    acc2 = __builtin_amdgcn_mfma_f32_16x16x32_bf16(ah, b2l, acc2, 0, 0, 0);
    acc3 = __builtin_amdgcn_mfma_f32_16x16x32_bf16(ah, b3l, acc3, 0, 0, 0);
  }

  // D layout: row (=step offset) = kg*4 + r, col (=row offset) = m
  f32x4 accs[4] = {acc0, acc1, acc2, acc3};
#pragma unroll
  for (int nt = 0; nt < 4; ++nt) {
#pragma unroll
    for (int r = 0; r < 4; ++r) {
      const int step = (tstep + kg * 4 + r) & (RING_D - 1);
      ring[step * 256 + q * 64 + nt * 16 + m] = accs[nt][r];
    }
  }
}

// ---------------------------------------------------------------------------
// Fused LSTM: recurrence (round-2 tagged-slot protocol, 4 WGs/batch) with
// the input GEMM folded into the per-step idle latency windows.
// Each wave produces its OWN gate's G-rows into a wave-private LDS ring
// (no cross-wave ring dependency). Production is placed after wave-0's
// publish and before waves-1..3's poll, overlapping the exchange RT.
// Exchange protocol is byte-identical to the verified round-2 kernel.
// ---------------------------------------------------------------------------
__global__ __launch_bounds__(256, 1) void lstm_fused(
    const short* __restrict__ Xhi, const short* __restrict__ Xlo,
    const short* __restrict__ WihHi, const short* __restrict__ WihLo,
    const float* __restrict__ bih, const float* __restrict__ bhh,
    const float* __restrict__ Whh,
    short* __restrict__ HShi, short* __restrict__ HSlo,
    unsigned long long* __restrict__ hslots) {  // [2][B][256] tagged h
  const int tid  = threadIdx.x;
  const int part = blockIdx.x >> 6;   // h-slice (XCD co-location: all 4
  const int b    = blockIdx.x & 63;   //  parts of batch b are == b mod 8)
  const int q    = tid >> 6;          // wave: gate 0=i 1=f 2=g 3=o
  const int l    = tid & 63;
  const int hidx = part * 64 + l;
  const int j    = q * 256 + hidx;    // W_hh row / gate index

  float w[256];
  {
    const float* wr = Whh + (size_t)j * 256;
#pragma unroll
    for (int k = 0; k < 256; k += 4) {
      float4 v = *(const float4*)(wr + k);
      w[k] = v.x; w[k + 1] = v.y; w[k + 2] = v.z; w[k + 3] = v.w;
    }
  }
  const float bias_j = bih[j] + bhh[j];

  __shared__ float4 h_s4[64];
  float* h_s = (float*)h_s4;
  __shared__ float gate_s[4][64];
  __shared__ float ring[RING_D * 256];   // 64 KiB, wave-private columns

  // remote-index map for poller threads (waves 1..3 cover the 192 indices
  // outside this part's slice; wave 0 only produces)
  const int ctid = tid - 64;
  const int ridx = (ctid < part * 64) ? ctid : ctid + 64;

  unsigned long long* slot0 = hslots + (size_t)b * HSZ;
  const size_t slot_stride = (size_t)BATCH * HSZ;

  if (tid < 64) h_s4[tid] = make_float4(0.f, 0.f, 0.f, 0.f);
  float c = 0.f;

  // prologue: produce G for steps [0, 48)
  produce_gtile(Xhi, Xlo, WihHi, WihLo, ring, 0,  b, q, part, l);
  produce_gtile(Xhi, Xlo, WihHi, WihLo, ring, 16, b, q, part, l);
  produce_gtile(Xhi, Xlo, WihHi, WihLo, ring, 32, b, q, part, l);
  __syncthreads();

  for (int t = 0; t < T_STEPS; ++t) {
    const float gv = ring[(t & (RING_D - 1)) * 256 + q * 64 + l];

    float a0 = 0.f, a1 = 0.f, a2 = 0.f, a3 = 0.f;
#pragma unroll
    for (int k = 0; k < 256; k += 4) {
      const float4 hv = h_s4[k >> 2];   // wave-uniform LDS broadcast
      a0 = __builtin_fmaf(hv.x, w[k],     a0);
      a1 = __builtin_fmaf(hv.y, w[k + 1], a1);
      a2 = __builtin_fmaf(hv.z, w[k + 2], a2);
      a3 = __builtin_fmaf(hv.w, w[k + 3], a3);
    }
    const float pre = (gv + bias_j) + ((a0 + a1) + (a2 + a3));
    // per-wave activation: wave q==2 tanh, others sigmoid (wave-uniform)
    gate_s[q][l] = (q == 2) ? tanh_fast(pre) : 1.f / (1.f + __expf(-pre));
    __syncthreads();  // (1) activated gates ready

    const unsigned exp_tag = (unsigned)(t + 1);
    unsigned long long* slot = slot0 + (size_t)(t & 1) * slot_stride;
    const bool do_prod = ((t & 15) == 0) && (t + RING_D <= T_STEPS);

    if (q == 0) {
      // producer: combine gates, emit h, publish FIRST (RT starts now)
      const float si = gate_s[0][l];
      const float sf = gate_s[1][l];
      const float tg = gate_s[2][l];
      const float so = gate_s[3][l];
      c = sf * c + si * tg;
      const float h = so * tanh_fast(c);
      const size_t oidx = ((size_t)t * BATCH + b) * HSZ + hidx;
      const unsigned short hb = f32_to_bf16(h);
      const unsigned short lb = f32_to_bf16(h - bf16_to_f32(hb));
      HShi[oidx] = (short)hb;
      HSlo[oidx] = (short)lb;
      h_s[hidx] = h;                    // own slice: straight to LDS
      const unsigned long long pk =
          ((unsigned long long)exp_tag << 32) | (unsigned)__float_as_uint(h);
      __hip_atomic_store(slot + hidx, pk, __ATOMIC_RELAXED,
                         __HIP_MEMORY_SCOPE_AGENT);
    }

    // G production burst: wave 0 after publish (store drains in background);
    // waves 1-3 before their poll (burst time eats the exchange RT).
    if (do_prod)
      produce_gtile(Xhi, Xlo, WihHi, WihLo, ring, t + (RING_D - 16),
                    b, q, part, l);

    if (q != 0 && t + 1 < T_STEPS) {
      unsigned long long v;
      do {
        v = __hip_atomic_load(slot + ridx, __ATOMIC_RELAXED,
                              __HIP_MEMORY_SCOPE_AGENT);
      } while ((unsigned)(v >> 32) != exp_tag);
      h_s[ridx] = __uint_as_float((unsigned)v);
    }
    __syncthreads();  // (2) h_s ready for next step
  }
}

// ---------------------------------------------------------------------------
// kernel_launch: single-pass pipeline (no chunking; ws proven >= 940 MB).
// split W/X -> lstm_fused (recurrence + fused input GEMM) -> FC GEMM.
// ---------------------------------------------------------------------------
extern "C" void kernel_launch(void* const* d_in, const int* in_sizes, int n_in,
                              void* d_out, int out_size, void* d_ws, size_t ws_size,
                              hipStream_t stream) {
  (void)in_sizes; (void)n_in; (void)out_size; (void)ws_size;
  const float* X   = (const float*)d_in[0];
  const float* Wih = (const float*)d_in[1];
  const float* Whh = (const float*)d_in[2];
  const float* bih = (const float*)d_in[3];
  const float* bhh = (const float*)d_in[4];
  const float* Wfc = (const float*)d_in[5];
  const float* bfc = (const float*)d_in[6];
  float* out = (float*)d_out;

  // ---- workspace layout (static): ~405 MB total ----
  char* p = (char*)d_ws;
  short* Xhi   = (short*)p;  p += (size_t)T_STEPS * BATCH * ISZ * 2;  // 134 MB
  short* Xlo   = (short*)p;  p += (size_t)T_STEPS * BATCH * ISZ * 2;  // 134 MB
  short* HShi  = (short*)p;  p += (size_t)T_STEPS * BATCH * HSZ * 2;  //  67 MB
  short* HSlo  = (short*)p;  p += (size_t)T_STEPS * BATCH * HSZ * 2;  //  67 MB
  short* WihHi = (short*)p;  p += 1048576UL;
  short* WihLo = (short*)p;  p += 1048576UL;
  short* WfcHi = (short*)p;  p += 65536UL;
  short* WfcLo = (short*)p;  p += 65536UL;
  unsigned long long* hslots = (unsigned long long*)p;                // 256 KB

  // zero hslots (stale tags would falsely satisfy polls on re-launch)
  zero_u32_kernel<<<256, 256, 0, stream>>>((unsigned int*)hslots, 65536);
  // weight splits
  split_bf16_kernel<<<512, 256, 0, stream>>>(Wih, WihHi, WihLo, 524288L);
  split_bf16_kernel<<<32, 256, 0, stream>>>(Wfc, WfcHi, WfcLo, 32768L);
  // full-T X split: 2048*64*512 = 67,108,864 elems -> 65536 blocks
  split_bf16_kernel<<<65536, 256, 0, stream>>>(X, Xhi, Xlo, 67108864L);

  // fused recurrence + input GEMM
  lstm_fused<<<256, 256, 0, stream>>>(Xhi, Xlo, WihHi, WihLo, bih, bhh, Whh,
                                      HShi, HSlo, hslots);

  // out = HS @ Wfc^T + bfc  [M=131072, N=128, K=256]
  gemm_bf16x3<<<dim3(T_STEPS, 2), 256, 0, stream>>>(HShi, HSlo, WfcHi, WfcLo,
                                                    bfc, nullptr, out,
                                                    128, 256);
}

// Round 5
// 8740.354 us; speedup vs baseline: 4.6254x; 1.1426x over previous
//
#include <hip/hip_runtime.h>

// Problem constants
#define T_STEPS 2048
#define BATCH   64
#define ISZ     512
#define HSZ     256
#define G4      1024   // 4*H
#define OSZ     128

typedef __attribute__((ext_vector_type(8))) short short8;
typedef __attribute__((ext_vector_type(4))) float f32x4;

__device__ __forceinline__ unsigned short f32_to_bf16(float x) {
  unsigned int u = __float_as_uint(x);
  unsigned int r = (u + 0x7FFFu + ((u >> 16) & 1u)) >> 16;  // RTNE
  return (unsigned short)r;
}
__device__ __forceinline__ float bf16_to_f32(unsigned short s) {
  return __uint_as_float(((unsigned int)s) << 16);
}
__device__ __forceinline__ float tanh_fast(float x) {
  return 1.f - 2.f / (__expf(2.f * x) + 1.f);
}

// ---------------------------------------------------------------------------
// fp32 -> bf16 hi + bf16 residual lo. n must be %4.
// ---------------------------------------------------------------------------
__global__ void split_bf16_kernel(const float* __restrict__ src,
                                  short* __restrict__ hi, short* __restrict__ lo,
                                  long n) {
  long i = ((long)blockIdx.x * blockDim.x + threadIdx.x) * 4;
  if (i >= n) return;
  float4 v = *(const float4*)(src + i);
  float xs[4] = {v.x, v.y, v.z, v.w};
  short h[4], l[4];
#pragma unroll
  for (int j = 0; j < 4; ++j) {
    unsigned short hb = f32_to_bf16(xs[j]);
    float hf = bf16_to_f32(hb);
    unsigned short lb = f32_to_bf16(xs[j] - hf);
    h[j] = (short)hb; l[j] = (short)lb;
  }
  *(short4*)(hi + i) = make_short4(h[0], h[1], h[2], h[3]);
  *(short4*)(lo + i) = make_short4(l[0], l[1], l[2], l[3]);
}

__global__ void zero_u32_kernel(unsigned int* __restrict__ p, int n) {
  int i = blockIdx.x * blockDim.x + threadIdx.x;
  if (i < n) p[i] = 0u;
}

// ---------------------------------------------------------------------------
// Split-bf16 GEMM (used for FC epilogue): C = A*B^T + bias, fp32 out.
// WG=4 waves, tile 64x64, grid (m-tiles, n-tiles).
// ---------------------------------------------------------------------------
__global__ __launch_bounds__(256) void gemm_bf16x3(
    const short* __restrict__ Ahi, const short* __restrict__ Alo,
    const short* __restrict__ Bhi, const short* __restrict__ Blo,
    const float* __restrict__ bias1, const float* __restrict__ bias2,
    float* __restrict__ C, int N, int K) {
  const int tid  = threadIdx.x;
  const int lane = tid & 63;
  const int wv   = tid >> 6;
  const int lrow = lane & 15;
  const int kgrp = lane >> 4;
  const int m0 = blockIdx.x * 64 + wv * 16;
  const int n0 = blockIdx.y * 64;

  const short* pah = Ahi + (size_t)(m0 + lrow) * K + kgrp * 8;
  const short* pal = Alo + (size_t)(m0 + lrow) * K + kgrp * 8;
  const short* pbh = Bhi + (size_t)(n0 + lrow) * K + kgrp * 8;
  const short* pbl = Blo + (size_t)(n0 + lrow) * K + kgrp * 8;
  const size_t cs = (size_t)16 * K;

  f32x4 acc0 = {0.f, 0.f, 0.f, 0.f};
  f32x4 acc1 = acc0, acc2 = acc0, acc3 = acc0;

  for (int kb = 0; kb < K; kb += 32) {
    short8 ah  = *(const short8*)(pah + kb);
    short8 al  = *(const short8*)(pal + kb);
    short8 b0h = *(const short8*)(pbh + kb);
    short8 b0l = *(const short8*)(pbl + kb);
    short8 b1h = *(const short8*)(pbh + cs + kb);
    short8 b1l = *(const short8*)(pbl + cs + kb);
    short8 b2h = *(const short8*)(pbh + 2 * cs + kb);
    short8 b2l = *(const short8*)(pbl + 2 * cs + kb);
    short8 b3h = *(const short8*)(pbh + 3 * cs + kb);
    short8 b3l = *(const short8*)(pbl + 3 * cs + kb);

    acc0 = __builtin_amdgcn_mfma_f32_16x16x32_bf16(ah, b0h, acc0, 0, 0, 0);
    acc1 = __builtin_amdgcn_mfma_f32_16x16x32_bf16(ah, b1h, acc1, 0, 0, 0);
    acc2 = __builtin_amdgcn_mfma_f32_16x16x32_bf16(ah, b2h, acc2, 0, 0, 0);
    acc3 = __builtin_amdgcn_mfma_f32_16x16x32_bf16(ah, b3h, acc3, 0, 0, 0);
    acc0 = __builtin_amdgcn_mfma_f32_16x16x32_bf16(al, b0h, acc0, 0, 0, 0);
    acc1 = __builtin_amdgcn_mfma_f32_16x16x32_bf16(al, b1h, acc1, 0, 0, 0);
    acc2 = __builtin_amdgcn_mfma_f32_16x16x32_bf16(al, b2h, acc2, 0, 0, 0);
    acc3 = __builtin_amdgcn_mfma_f32_16x16x32_bf16(al, b3h, acc3, 0, 0, 0);
    acc0 = __builtin_amdgcn_mfma_f32_16x16x32_bf16(ah, b0l, acc0, 0, 0, 0);
    acc1 = __builtin_amdgcn_mfma_f32_16x16x32_bf16(ah, b1l, acc1, 0, 0, 0);
    acc2 = __builtin_amdgcn_mfma_f32_16x16x32_bf16(ah, b2l, acc2, 0, 0, 0);
    acc3 = __builtin_amdgcn_mfma_f32_16x16x32_bf16(ah, b3l, acc3, 0, 0, 0);
  }

  f32x4 accs[4] = {acc0, acc1, acc2, acc3};
#pragma unroll
  for (int c = 0; c < 4; ++c) {
    const int col = n0 + c * 16 + lrow;
    float bs = bias1[col];
    if (bias2) bs += bias2[col];
#pragma unroll
    for (int r = 0; r < 4; ++r) {
      const int row = m0 + kgrp * 4 + r;
      C[(size_t)row * N + col] = accs[c][r] + bs;
    }
  }
}

// ---------------------------------------------------------------------------
// A-stationary input GEMM: G[M][1024] = X[M][512]*Wih[1024][512]^T + bih+bhh.
// One WG per 64-row m-tile (grid = M/64). A-fragments (hi+lo, 16 k-blocks)
// loaded ONCE into ~128 VGPRs, then all 16 n-tiles stream B from L2.
// A HBM traffic drops 16x vs the (CH,16)-grid version. MFMA chain and
// accumulation order identical to gemm_bf16x3 -> bit-identical output.
// ---------------------------------------------------------------------------
__global__ __launch_bounds__(256) void gemm_ih_astat(
    const short* __restrict__ Ahi, const short* __restrict__ Alo,
    const short* __restrict__ Bhi, const short* __restrict__ Blo,
    const float* __restrict__ bias1, const float* __restrict__ bias2,
    float* __restrict__ C) {
  const int tid  = threadIdx.x;
  const int lane = tid & 63;
  const int wv   = tid >> 6;
  const int lrow = lane & 15;
  const int kgrp = lane >> 4;
  const int m0 = blockIdx.x * 64 + wv * 16;
  const size_t cs = (size_t)16 * ISZ;

  // ---- load A fragments once: 16 k-blocks x (hi,lo) short8 = 128 VGPRs ----
  short8 ah[16], al[16];
  {
    const short* pa = Ahi + (size_t)(m0 + lrow) * ISZ + kgrp * 8;
    const short* pl = Alo + (size_t)(m0 + lrow) * ISZ + kgrp * 8;
#pragma unroll
    for (int kb = 0; kb < 16; ++kb) {
      ah[kb] = *(const short8*)(pa + kb * 32);
      al[kb] = *(const short8*)(pl + kb * 32);
    }
  }

  for (int n0 = 0; n0 < G4; n0 += 64) {
    const short* pbh = Bhi + (size_t)(n0 + lrow) * ISZ + kgrp * 8;
    const short* pbl = Blo + (size_t)(n0 + lrow) * ISZ + kgrp * 8;

    f32x4 acc0 = {0.f, 0.f, 0.f, 0.f};
    f32x4 acc1 = acc0, acc2 = acc0, acc3 = acc0;

#pragma unroll
    for (int kb = 0; kb < 16; ++kb) {
      const int ko = kb * 32;
      short8 b0h = *(const short8*)(pbh + ko);
      short8 b0l = *(const short8*)(pbl + ko);
      short8 b1h = *(const short8*)(pbh + cs + ko);
      short8 b1l = *(const short8*)(pbl + cs + ko);
      short8 b2h = *(const short8*)(pbh + 2 * cs + ko);
      short8 b2l = *(const short8*)(pbl + 2 * cs + ko);
      short8 b3h = *(const short8*)(pbh + 3 * cs + ko);
      short8 b3l = *(const short8*)(pbl + 3 * cs + ko);

      acc0 = __builtin_amdgcn_mfma_f32_16x16x32_bf16(ah[kb], b0h, acc0, 0, 0, 0);
      acc1 = __builtin_amdgcn_mfma_f32_16x16x32_bf16(ah[kb], b1h, acc1, 0, 0, 0);
      acc2 = __builtin_amdgcn_mfma_f32_16x16x32_bf16(ah[kb], b2h, acc2, 0, 0, 0);
      acc3 = __builtin_amdgcn_mfma_f32_16x16x32_bf16(ah[kb], b3h, acc3, 0, 0, 0);
      acc0 = __builtin_amdgcn_mfma_f32_16x16x32_bf16(al[kb], b0h, acc0, 0, 0, 0);
      acc1 = __builtin_amdgcn_mfma_f32_16x16x32_bf16(al[kb], b1h, acc1, 0, 0, 0);
      acc2 = __builtin_amdgcn_mfma_f32_16x16x32_bf16(al[kb], b2h, acc2, 0, 0, 0);
      acc3 = __builtin_amdgcn_mfma_f32_16x16x32_bf16(al[kb], b3h, acc3, 0, 0, 0);
      acc0 = __builtin_amdgcn_mfma_f32_16x16x32_bf16(ah[kb], b0l, acc0, 0, 0, 0);
      acc1 = __builtin_amdgcn_mfma_f32_16x16x32_bf16(ah[kb], b1l, acc1, 0, 0, 0);
      acc2 = __builtin_amdgcn_mfma_f32_16x16x32_bf16(ah[kb], b2l, acc2, 0, 0, 0);
      acc3 = __builtin_amdgcn_mfma_f32_16x16x32_bf16(ah[kb], b3l, acc3, 0, 0, 0);
    }

    f32x4 accs[4] = {acc0, acc1, acc2, acc3};
#pragma unroll
    for (int c = 0; c < 4; ++c) {
      const int col = n0 + c * 16 + lrow;
      const float bs = bias1[col] + bias2[col];
#pragma unroll
      for (int r = 0; r < 4; ++r) {
        const int row = m0 + kgrp * 4 + r;
        C[(size_t)row * G4 + col] = accs[c][r] + bs;
      }
    }
  }
}

// ---------------------------------------------------------------------------
// LSTM recurrence over one chunk — ROUND-2 VERIFIED KERNEL, byte-identical.
// 4 WGs/batch x 64 batches = 256 WGs; w[256]/thread; tagged uint64 h-slots.
// ---------------------------------------------------------------------------
__global__ __launch_bounds__(256, 1) void lstm_rec(
    const float* __restrict__ G,        // [nsteps][B][1024] (chunk)
    const float* __restrict__ Whh,      // [1024][256]
    short* __restrict__ HShi, short* __restrict__ HSlo,  // [nsteps][B][256]
    unsigned long long* __restrict__ hslots,  // [2][B][256] tagged h
    float* __restrict__ c_buf,          // [B][256]
    int t0, int nsteps) {
  const int tid  = threadIdx.x;
  const int part = blockIdx.x >> 6;   // which 64 h-indices
  const int b    = blockIdx.x & 63;   // batch
  const int q    = tid >> 6;          // wave: gate 0=i 1=f 2=g 3=o
  const int l    = tid & 63;
  const int hidx = part * 64 + l;
  const int j    = q * 256 + hidx;    // W_hh row / gate index

  float w[256];
  {
    const float* wr = Whh + (size_t)j * 256;
#pragma unroll
    for (int k = 0; k < 256; k += 4) {
      float4 v = *(const float4*)(wr + k);
      w[k] = v.x; w[k + 1] = v.y; w[k + 2] = v.z; w[k + 3] = v.w;
    }
  }

  __shared__ float4 h_s4[64];
  float* h_s = (float*)h_s4;
  __shared__ float gate_s[4][64];

  const int ctid = tid - 64;
  const int ridx = (ctid < part * 64) ? ctid : ctid + 64;

  unsigned long long* slot0 = hslots + (size_t)b * HSZ;  // parity-0 base
  const size_t slot_stride = (size_t)BATCH * HSZ;        // parity stride

  // ---- initial h_s fill ----
  if (t0 == 0) {
    if (tid < 64) h_s4[tid] = make_float4(0.f, 0.f, 0.f, 0.f);
  } else {
    unsigned long long* ap =
        slot0 + (size_t)((t0 + 1) & 1) * slot_stride + tid;
    unsigned long long v;
    do {
      v = __hip_atomic_load(ap, __ATOMIC_RELAXED, __HIP_MEMORY_SCOPE_AGENT);
    } while ((unsigned)(v >> 32) != (unsigned)t0);
    h_s[tid] = __uint_as_float((unsigned)v);
  }
  float c = 0.f;
  if (q == 0 && t0 > 0) c = c_buf[(size_t)b * HSZ + hidx];

  const float* gbase = G + (size_t)b * G4 + j;
  float gcur = gbase[0];
  __syncthreads();

  for (int t = 0; t < nsteps; ++t) {
    const size_t tn = (t + 1 < nsteps) ? (size_t)(t + 1) : (size_t)(nsteps - 1);
    const float gnx = gbase[tn * (size_t)(BATCH * G4)];  // prefetch next step

    float a0 = 0.f, a1 = 0.f, a2 = 0.f, a3 = 0.f;
#pragma unroll
    for (int k = 0; k < 256; k += 4) {
      const float4 hv = h_s4[k >> 2];   // wave-uniform LDS broadcast
      a0 = __builtin_fmaf(hv.x, w[k],     a0);
      a1 = __builtin_fmaf(hv.y, w[k + 1], a1);
      a2 = __builtin_fmaf(hv.z, w[k + 2], a2);
      a3 = __builtin_fmaf(hv.w, w[k + 3], a3);
    }
    const float pre = gcur + ((a0 + a1) + (a2 + a3));
    // per-wave activation: wave q==2 tanh, others sigmoid (wave-uniform)
    gate_s[q][l] = (q == 2) ? tanh_fast(pre) : 1.f / (1.f + __expf(-pre));
    gcur = gnx;
    __syncthreads();  // (1) activated gates ready

    const unsigned exp_tag = (unsigned)(t0 + t + 1);
    unsigned long long* slot =
        slot0 + (size_t)((t0 + t) & 1) * slot_stride;

    if (q == 0) {
      // producer: combine gates, emit h
      const float si = gate_s[0][l];
      const float sf = gate_s[1][l];
      const float tg = gate_s[2][l];
      const float so = gate_s[3][l];
      c = sf * c + si * tg;
      const float h = so * tanh_fast(c);
      const size_t oidx = ((size_t)t * BATCH + b) * HSZ + hidx;
      const unsigned short hb = f32_to_bf16(h);
      const unsigned short lb = f32_to_bf16(h - bf16_to_f32(hb));
      HShi[oidx] = (short)hb;
      HSlo[oidx] = (short)lb;
      h_s[hidx] = h;                    // own slice: straight to LDS
      const unsigned long long pk =
          ((unsigned long long)exp_tag << 32) | (unsigned)__float_as_uint(h);
      __hip_atomic_store(slot + hidx, pk, __ATOMIC_RELAXED,
                         __HIP_MEMORY_SCOPE_AGENT);
    } else if (t + 1 < nsteps) {
      // consumers: poll remote tagged values (overlaps producer's nonlin)
      unsigned long long v;
      do {
        v = __hip_atomic_load(slot + ridx, __ATOMIC_RELAXED,
                              __HIP_MEMORY_SCOPE_AGENT);
      } while ((unsigned)(v >> 32) != exp_tag);
      h_s[ridx] = __uint_as_float((unsigned)v);
    }
    __syncthreads();  // (2) h_s ready for next step
  }

  if (q == 0) c_buf[(size_t)b * HSZ + hidx] = c;  // persist c across chunks
}

// ---------------------------------------------------------------------------
// kernel_launch: chunked pipeline sized to ws_size.
// Per chunk (CH steps): split X -> A-stationary GEMM -> lstm_rec -> FC GEMM.
// ---------------------------------------------------------------------------
extern "C" void kernel_launch(void* const* d_in, const int* in_sizes, int n_in,
                              void* d_out, int out_size, void* d_ws, size_t ws_size,
                              hipStream_t stream) {
  (void)in_sizes; (void)n_in; (void)out_size;
  const float* X   = (const float*)d_in[0];
  const float* Wih = (const float*)d_in[1];
  const float* Whh = (const float*)d_in[2];
  const float* bih = (const float*)d_in[3];
  const float* bhh = (const float*)d_in[4];
  const float* Wfc = (const float*)d_in[5];
  const float* bfc = (const float*)d_in[6];
  float* out = (float*)d_out;

  // ---- choose chunk size (largest pow2 dividing T that fits ws_size) ----
  const size_t fixed =
      2UL * 1048576UL   /* Wih hi+lo  */ +
      2UL * 65536UL     /* Wfc hi+lo  */ +
      262144UL          /* hslots     */ +
      65536UL;          /* c_buf      */
  const size_t per_step =
      (size_t)BATCH * G4 * 4   /* Gc   262144 */ +
      2UL * BATCH * ISZ * 2    /* Xhi+Xlo 131072 */ +
      2UL * BATCH * HSZ * 2    /* HShi+HSlo 65536 */;
  int CH = 2048;
  while (CH > 16 && fixed + (size_t)CH * per_step > ws_size) CH >>= 1;

  // ---- workspace layout ----
  char* p = (char*)d_ws;
  float* Gc    = (float*)p;  p += (size_t)CH * BATCH * G4 * 4;
  short* Xhi   = (short*)p;  p += (size_t)CH * BATCH * ISZ * 2;
  short* Xlo   = (short*)p;  p += (size_t)CH * BATCH * ISZ * 2;
  short* HShi  = (short*)p;  p += (size_t)CH * BATCH * HSZ * 2;
  short* HSlo  = (short*)p;  p += (size_t)CH * BATCH * HSZ * 2;
  short* WihHi = (short*)p;  p += 1048576UL;
  short* WihLo = (short*)p;  p += 1048576UL;
  short* WfcHi = (short*)p;  p += 65536UL;
  short* WfcLo = (short*)p;  p += 65536UL;
  unsigned long long* hslots = (unsigned long long*)p;  p += 262144UL;
  float* c_buf = (float*)p;

  // ---- init: zero hslots (stale tags would falsely satisfy polls) ----
  zero_u32_kernel<<<256, 256, 0, stream>>>((unsigned int*)hslots, 65536);
  // weight splits
  split_bf16_kernel<<<512, 256, 0, stream>>>(Wih, WihHi, WihLo, 524288L);
  split_bf16_kernel<<<32, 256, 0, stream>>>(Wfc, WfcHi, WfcLo, 32768L);

  const long xchunk_elems = (long)CH * BATCH * ISZ;   // CH*32768
  for (int c0 = 0; c0 < T_STEPS; c0 += CH) {
    const float* Xc = X + (size_t)c0 * BATCH * ISZ;
    split_bf16_kernel<<<(int)(xchunk_elems / 1024), 256, 0, stream>>>(
        Xc, Xhi, Xlo, xchunk_elems);
    // G = Xc @ Wih^T + (bih + bhh)  [M=CH*64, N=1024, K=512], A-stationary
    gemm_ih_astat<<<CH, 256, 0, stream>>>(Xhi, Xlo, WihHi, WihLo,
                                          bih, bhh, Gc);
    lstm_rec<<<256, 256, 0, stream>>>(Gc, Whh, HShi, HSlo, hslots, c_buf,
                                      c0, CH);
    // out_chunk = HS @ Wfc^T + bfc  [M=CH*64, N=128, K=256]
    gemm_bf16x3<<<dim3(CH, 2), 256, 0, stream>>>(HShi, HSlo, WfcHi, WfcLo,
                                                 bfc, nullptr,
                                                 out + (size_t)c0 * BATCH * OSZ,
                                                 128, 256);
  }
}